// Round 9
// baseline (154.785 us; speedup 1.0000x reference)
//
#include <hip/hip_runtime.h>
#include <math.h>

// Problem dims
#define NB 64
#define NA 23
#define NT 128
#define ND 256
#define NAE 32
#define NS 6
#define NH 8
#define NDM 288

typedef float v2f __attribute__((ext_vector_type(2)));
__device__ __forceinline__ v2f pkfma(v2f a, v2f b, v2f c) {
    return __builtin_elementwise_fma(a, b, c);   // v_pk_fma_f32
}

// Workspace layout (float offsets) — max used 134400 < 135120 budget.
// PEKT2: j-pair interleaved: float index (j>>1)*256 + t*2 + (j&1)
#define OFF_PEK    0        // PEKT2 : 256*128
#define OFF_PECUM  32768    // PEcum[L-1][e] : 128*256 (inclusive prefix over t)
// WkT2: j-pair interleaved: float index (j>>1)*512 + e*2 + (j&1)
#define OFF_WKT    65536    // WkT2 : 256*256
#define OFF_VWO    131072   // VWo[h][e<256] : 8*256
#define OFF_PEMV   133120   // PEMV[h][t] = sum_e pe[e][t]*VWo[h][e] : 8*128
#define OFF_EVA    134144   // evvA[a][h] : 23*8
#define OFF_CST    134328   // [0..5]=sWf, [6]=b_static.Wg1+bg, [7]=bo.Wg0
#define OFF_SB     134336   // per-b atomic sums : 64

// ---------------- setup1: 393 blocks ----------------
__global__ __launch_bounds__(256) void setup1_kernel(
    const float* __restrict__ Wk, const float* __restrict__ Wv,
    const float* __restrict__ Wo, const float* __restrict__ Wg,
    const float* __restrict__ bv, const float* __restrict__ bo,
    const float* __restrict__ W_static, const float* __restrict__ b_static,
    const float* __restrict__ bg, const float* __restrict__ E_var,
    float* __restrict__ ws)
{
    const int blk = blockIdx.x;
    const int tid = threadIdx.x;
    float* PEcum = ws + OFF_PECUM;
    float* WkT   = ws + OFF_WKT;
    float* VWo   = ws + OFF_VWO;
    float* cst   = ws + OFF_CST;

    if (blk < 128) {
        const int g = tid >> 7, t = tid & 127;
        const int e = blk * 2 + g;
        const int i = e >> 1;
        const float kdiv = 0.07195578415606394f; // ln(10000)/128
        const float dv = expf(-(float)i * kdiv);
        const float ang = (float)t * dv;
        const float v = (e & 1) ? cosf(ang) : sinf(ang);
        __shared__ float buf[256];
        buf[tid] = v;
        #pragma unroll
        for (int s = 1; s < 128; s <<= 1) {
            __syncthreads();
            float add = (t >= s) ? buf[tid - s] : 0.f;
            __syncthreads();
            buf[tid] += add;
        }
        __syncthreads();
        PEcum[t * ND + e] = buf[tid];   // row (L-1) holds sum_{t'<L}
    } else if (blk < 384) {
        const int j = blk - 128;
        const float scale = 0.17677669529663687f;
        // j-pair interleaved for packed D loads
        WkT[(j >> 1) * 512 + tid * 2 + (j & 1)] = Wk[tid * ND + j] * scale;
    } else if (blk < 392) {
        const int h = blk - 384;
        __shared__ float wog[32];    // WoWg[h*32+jj]
        __shared__ float vext[32];   // VWo rows 256..287
        __shared__ float vbS;
        {
            const int jj = tid >> 3, sub = tid & 7;
            const int j = h * 32 + jj;
            float acc = 0.f;
            const int m0 = sub * 36;
            #pragma unroll 4
            for (int m = m0; m < m0 + 36; ++m)
                acc = fmaf(Wo[j * NDM + m], Wg[m], acc);
            acc += __shfl_down(acc, 4, 8);
            acc += __shfl_down(acc, 2, 8);
            acc += __shfl_down(acc, 1, 8);
            if (sub == 0) wog[jj] = acc;
        }
        __syncthreads();
        {
            float acc = 0.f;
            #pragma unroll 8
            for (int jj = 0; jj < 32; ++jj)
                acc = fmaf(Wv[tid * ND + h * 32 + jj], wog[jj], acc);
            VWo[h * 256 + tid] = acc;
        }
        if (tid < 32) {
            float acc = 0.f;
            #pragma unroll 8
            for (int jj = 0; jj < 32; ++jj)
                acc = fmaf(Wv[(256 + tid) * ND + h * 32 + jj], wog[jj], acc);
            vext[tid] = acc;
        }
        if (tid == 0) {
            float acc = 0.f;
            #pragma unroll 8
            for (int jj = 0; jj < 32; ++jj)
                acc = fmaf(bv[h * 32 + jj], wog[jj], acc);
            vbS = acc;
        }
        __syncthreads();
        if (tid < NA) {
            float acc = vbS;
            #pragma unroll 8
            for (int ee = 0; ee < 32; ++ee)
                acc = fmaf(E_var[tid * NAE + ee], vext[ee], acc);
            ws[OFF_EVA + tid * NH + h] = acc;
        }
    } else {
        const int i = tid >> 5, sub = tid & 31;
        float acc = 0.f;
        if (i < 6) {
            for (int m = sub; m < 256; m += 32)
                acc = fmaf(W_static[i * ND + m], Wg[NDM + m], acc);
        } else if (i == 6) {
            for (int m = sub; m < 256; m += 32)
                acc = fmaf(b_static[m], Wg[NDM + m], acc);
        } else {
            for (int m = sub; m < NDM; m += 32)
                acc = fmaf(bo[m], Wg[m], acc);
        }
        #pragma unroll
        for (int off = 16; off > 0; off >>= 1)
            acc += __shfl_down(acc, off, 32);
        if (sub == 0) cst[i] = (i == 6) ? acc + bg[0] : acc;
    }
}

// ---------------- setup2: 128 blocks (one per t) ----------------
__global__ __launch_bounds__(256) void setup2_kernel(
    const float* __restrict__ Wk, float* __restrict__ ws)
{
    const int t = blockIdx.x;
    const int tid = threadIdx.x;
    __shared__ float peS[256];
    {
        const int i = tid >> 1;
        const float kdiv = 0.07195578415606394f;
        const float dv = expf(-(float)i * kdiv);
        const float ang = (float)t * dv;
        peS[tid] = (tid & 1) ? cosf(ang) : sinf(ang);
    }
    __syncthreads();
    {   // PEKT2[(j>>1)][t][j&1], j = tid
        float a0 = 0.f, a1 = 0.f, a2 = 0.f, a3 = 0.f;
        #pragma unroll 4
        for (int e = 0; e < 256; e += 4) {
            a0 = fmaf(peS[e],     Wk[ e      * ND + tid], a0);
            a1 = fmaf(peS[e + 1], Wk[(e + 1) * ND + tid], a1);
            a2 = fmaf(peS[e + 2], Wk[(e + 2) * ND + tid], a2);
            a3 = fmaf(peS[e + 3], Wk[(e + 3) * ND + tid], a3);
        }
        const float scale = 0.17677669529663687f;
        ws[OFF_PEK + (tid >> 1) * 256 + t * 2 + (tid & 1)] =
            ((a0 + a1) + (a2 + a3)) * scale;
    }
    {
        const int h = tid >> 5, ee = tid & 31;
        const float* vw = ws + OFF_VWO + h * 256;
        float v = 0.f;
        #pragma unroll
        for (int k = 0; k < 8; ++k)
            v = fmaf(peS[ee + 32 * k], vw[ee + 32 * k], v);
        v += __shfl_down(v, 16, 32);
        v += __shfl_down(v, 8, 32);
        v += __shfl_down(v, 4, 32);
        v += __shfl_down(v, 2, 32);
        v += __shfl_down(v, 1, 32);
        if (ee == 0) ws[OFF_PEMV + h * NT + t] = v;
    }
    if (t == 0 && tid < NB) ws[OFF_SB + tid] = 0.f;   // reset atomic sums
}

// Phase E inner body (PACKED): KCNT t-values per thread, 4 heads (hh quad).
// Per iter: 2 b128 + 1 b64 LDS broadcasts, KCNT*4 pk_fma + KCNT scalar m-ops.
// Swizzle r=(e+(e>>6))&3 + padded Wb: conflict-free chunk reads (r8-measured 188K).
#define E_ITER(KCNT) do {                                                    \
    const int e = ebase + ee;                                                \
    const int r = (e + (e >> 6)) & 3;                                        \
    const float2 wb = Wb[half][e + (e >> 6)];                                \
    const float4 cq = comboV[e * 4 + (hh ^ r)];                              \
    const float4 cm = comboV[e * 4 + ((2 | hh) ^ r)];                        \
    const v2f cq01 = *(const v2f*)&cq;                                       \
    const v2f cq23 = *((const v2f*)&cq + 1);                                 \
    const v2f cm01 = *(const v2f*)&cm;                                       \
    const v2f cm23 = *((const v2f*)&cm + 1);                                 \
    const float m0 = fmaxf(fmaf(xt0, wb.x, wb.y), 0.f);                      \
    const float m1 = fmaxf(fmaf(xt1, wb.x, wb.y), 0.f);                      \
    const v2f m0v = {m0, m0}, m1v = {m1, m1};                                \
    aS2[0][0] = pkfma(m0v, cq01, aS2[0][0]);                                 \
    aS2[0][1] = pkfma(m0v, cq23, aS2[0][1]);                                 \
    aM2[0][0] = pkfma(m0v, cm01, aM2[0][0]);                                 \
    aM2[0][1] = pkfma(m0v, cm23, aM2[0][1]);                                 \
    aS2[1][0] = pkfma(m1v, cq01, aS2[1][0]);                                 \
    aS2[1][1] = pkfma(m1v, cq23, aS2[1][1]);                                 \
    aM2[1][0] = pkfma(m1v, cm01, aM2[1][0]);                                 \
    aM2[1][1] = pkfma(m1v, cm23, aM2[1][1]);                                 \
    if ((KCNT) == 4) {                                                       \
        const float m2 = fmaxf(fmaf(xt2, wb.x, wb.y), 0.f);                  \
        const float m3 = fmaxf(fmaf(xt3, wb.x, wb.y), 0.f);                  \
        const v2f m2v = {m2, m2}, m3v = {m3, m3};                            \
        aS2[2][0] = pkfma(m2v, cq01, aS2[2][0]);                             \
        aS2[2][1] = pkfma(m2v, cq23, aS2[2][1]);                             \
        aM2[2][0] = pkfma(m2v, cm01, aM2[2][0]);                             \
        aM2[2][1] = pkfma(m2v, cm23, aM2[2][1]);                             \
        aS2[3][0] = pkfma(m3v, cq01, aS2[3][0]);                             \
        aS2[3][1] = pkfma(m3v, cq23, aS2[3][1]);                             \
        aM2[3][0] = pkfma(m3v, cm01, aM2[3][0]);                             \
        aM2[3][1] = pkfma(m3v, cm23, aM2[3][1]);                             \
    }                                                                        \
} while (0)

// ---------------- main: one block = TWO wg's ----------------
__global__ __launch_bounds__(512) void main_kernel(
    const float* __restrict__ data, const int* __restrict__ lengths,
    const float* __restrict__ W_embed, const float* __restrict__ b_embed,
    const float* __restrict__ E_var,
    const float* __restrict__ Wq, const float* __restrict__ bq,
    float* __restrict__ ws)
{
    const int pair = blockIdx.x;          // 736 pairs
    const int tid  = threadIdx.x;         // 0..511
    const int half = tid >> 8;
    const int lt   = tid & 255;
    const int wgh  = pair * 2 + half;
    const int ah   = wgh % NA;
    const int bh   = wgh / NA;
    const int Lh   = lengths[wgh];        // uniform across the half's 4 waves

    __shared__ __align__(16) float xs[2][NT];
    __shared__ __align__(16) float qs[2][ND];
    __shared__ float2 Wb[2][ND + 4];      // padded index e+(e>>6)
    // combo[w]: rows e = 4 float4s {qk h0-3, qk h4-7, VWo h0-3, VWo h4-7}, swizzled.
    // combo[0][0..1024) = C scratch; combo[1][0..576) = ag alias;
    // after E: [0,1024)=sc, [1024,2048)=mvb, [2048,3072)=qkx per half.
    __shared__ __align__(16) float combo[2][ND * 16];
    __shared__ float red[2][4];

    const float* PEcum = ws + OFF_PECUM;
    const float* VWo   = ws + OFF_VWO;
    const float* cstp  = ws + OFF_CST;
    float* agA = &combo[1][0];            // ag[w][f] = agA[w*NDM + f]

    // ---- Phase A (per half) ----
    if (lt < NT) xs[half][lt] = data[wgh * NT + lt];
    __syncthreads();
    {
        const int e = lt;
        if (Lh > 0) {
            const float We = W_embed[ah * ND + e];
            const float be = b_embed[ah * ND + e];
            Wb[half][e + (e >> 6)] = make_float2(We, be);
            const float4* x4 = (const float4*)xs[half];
            float s0 = 0.f, s1 = 0.f, s2 = 0.f, s3 = 0.f;
            const int nq = Lh >> 2;
            for (int q = 0; q < nq; ++q) {
                const float4 xv = x4[q];
                s0 += fmaxf(fmaf(xv.x, We, be), 0.f);
                s1 += fmaxf(fmaf(xv.y, We, be), 0.f);
                s2 += fmaxf(fmaf(xv.z, We, be), 0.f);
                s3 += fmaxf(fmaf(xv.w, We, be), 0.f);
            }
            for (int t = nq * 4; t < Lh; ++t)
                s0 += fmaxf(fmaf(xs[half][t], We, be), 0.f);
            agA[half * NDM + e] = (((s0 + s1) + (s2 + s3)) + PEcum[(Lh - 1) * ND + e]) / (float)Lh;
        } else {
            Wb[half][e + (e >> 6)] = make_float2(0.f, 0.f);
            agA[half * NDM + e] = 0.f;
        }
    }
    if (lt < NAE) agA[half * NDM + ND + lt] = (Lh > 0) ? E_var[ah * NAE + lt] : 0.f;
    __syncthreads();

    // ---- Phase C: q for both wgs, Wq element read once ----
    {
        const int j = lt;
        const float4* a40 = (const float4*)(agA);
        const float4* a41 = (const float4*)(agA + NDM);
        const int fi0 = half * 36;
        float c0 = 0.f, c1 = 0.f, c2 = 0.f, c3 = 0.f;
        #pragma unroll 4
        for (int fi = fi0; fi < fi0 + 36; ++fi) {
            const float4 av0 = a40[fi];
            const float4 av1 = a41[fi];
            const int f = fi * 4;
            const float w0 = Wq[ f      * ND + j];
            const float w1 = Wq[(f + 1) * ND + j];
            const float w2 = Wq[(f + 2) * ND + j];
            const float w3 = Wq[(f + 3) * ND + j];
            c0 = fmaf(av0.x, w0, c0); c2 = fmaf(av0.y, w1, c2);
            c0 = fmaf(av0.z, w2, c0); c2 = fmaf(av0.w, w3, c2);
            c1 = fmaf(av1.x, w0, c1); c3 = fmaf(av1.y, w1, c3);
            c1 = fmaf(av1.z, w2, c1); c3 = fmaf(av1.w, w3, c3);
        }
        float* Csc = &combo[0][0];
        Csc[half * 512 +       j] = c0 + c2;
        Csc[half * 512 + 256 + j] = c1 + c3;
    }
    __syncthreads();
    {
        const float* Csc = &combo[0][0];
        qs[half][lt] = bq[lt] + Csc[half * 256 + lt] + Csc[512 + half * 256 + lt];
    }
    __syncthreads();

    // ---- Phase D (PACKED): WkT2 j-pair loads feed v_pk_fma_f32 ----
    {
        const int e = lt;
        const int hb = half;                 // heads hb*4 .. hb*4+3
        const v2f* wk2 = (const v2f*)(ws + OFF_WKT);
        const v2f* q20 = (const v2f*)(qs[0] + hb * 128);
        const v2f* q21 = (const v2f*)(qs[1] + hb * 128);
        float qk0[4], qk1[4];
        #pragma unroll
        for (int h4 = 0; h4 < 4; ++h4) {
            v2f a0 = {0.f, 0.f}, a1 = {0.f, 0.f};
            const v2f* wcol = wk2 + (hb * 64 + h4 * 16) * 256 + e;   // 8B/lane coalesced
            #pragma unroll
            for (int jp = 0; jp < 16; ++jp) {
                const v2f w  = wcol[jp * 256];
                const v2f q0 = q20[h4 * 16 + jp];
                const v2f q1 = q21[h4 * 16 + jp];
                a0 = pkfma(w, q0, a0);
                a1 = pkfma(w, q1, a1);
            }
            qk0[h4] = a0.x + a0.y;
            qk1[h4] = a1.x + a1.y;
        }
        const int r = (e + (e >> 6)) & 3;
        float4* row0 = (float4*)(&combo[0][0]) + e * 4;
        float4* row1 = (float4*)(&combo[1][0]) + e * 4;
        row0[hb ^ r] = make_float4(qk0[0], qk0[1], qk0[2], qk0[3]);
        row1[hb ^ r] = make_float4(qk1[0], qk1[1], qk1[2], qk1[3]);
        const float4 vw = make_float4(VWo[(hb * 4 + 0) * 256 + e],
                                      VWo[(hb * 4 + 1) * 256 + e],
                                      VWo[(hb * 4 + 2) * 256 + e],
                                      VWo[(hb * 4 + 3) * 256 + e]);
        row0[(2 | hb) ^ r] = vw;
        row1[(2 | hb) ^ r] = vw;
    }
    __syncthreads();

    // ---- Phase E: t-quad x e-chunk-in-wave; packed accumulators ----
    {
        const int lane = lt & 63;
        const int wv   = lt >> 6;        // wave id within half: 0..3
        const int hh   = wv & 1;         // head-quad
        const int tw   = wv >> 1;        // t-window
        const int t0   = lane & 15;
        const int c    = lane >> 4;      // e-chunk 0..3 (within wave)
        const int tb   = tw * 16 + t0;   // [0,32)
        const int ebase = c * 64;
        const float4* comboV = (const float4*)(&combo[half][0]);
        v2f aS2[4][2], aM2[4][2];        // [t-slot][h-pair]
        #pragma unroll
        for (int k = 0; k < 4; ++k)
            #pragma unroll
            for (int p = 0; p < 2; ++p) { aS2[k][p] = (v2f){0.f, 0.f}; aM2[k][p] = (v2f){0.f, 0.f}; }
        const float xt0 = xs[half][tb];
        const float xt1 = xs[half][tb + 32];
        const float xt2 = xs[half][tb + 64];
        const float xt3 = xs[half][tb + 96];
        if (Lh > 64) {
            #pragma unroll 4
            for (int ee = 0; ee < 64; ++ee) E_ITER(4);
        } else if (Lh > 0) {
            #pragma unroll 4
            for (int ee = 0; ee < 64; ++ee) E_ITER(2);
        }
        // sum across e-chunks c=0..3 via shfl (per 32-bit component)
        __syncthreads();   // all combo-row reads done -> reuse region (sync BEFORE writes)
        float* scF = &combo[half][0];        // sc[h*128+t]
        float* mvF = scF + 1024;             // mvb[h*128+t]
        #pragma unroll
        for (int k = 0; k < 4; ++k)
            #pragma unroll
            for (int p = 0; p < 2; ++p) {
                float sx = aS2[k][p].x, sy = aS2[k][p].y;
                float mx = aM2[k][p].x, my = aM2[k][p].y;
                sx += __shfl_down(sx, 32, 64); sx += __shfl_down(sx, 16, 64);
                sy += __shfl_down(sy, 32, 64); sy += __shfl_down(sy, 16, 64);
                mx += __shfl_down(mx, 32, 64); mx += __shfl_down(mx, 16, 64);
                my += __shfl_down(my, 32, 64); my += __shfl_down(my, 16, 64);
                if (c == 0) {
                    const int h = hh * 4 + p * 2;
                    scF[ h      * NT + tb + 32 * k] = sx;
                    scF[(h + 1) * NT + tb + 32 * k] = sy;
                    mvF[ h      * NT + tb + 32 * k] = mx;
                    mvF[(h + 1) * NT + tb + 32 * k] = my;
                }
            }
    }
    __syncthreads();

    // ---- qkx (PACKED, post-E, into freed combo[half][2048..3072)) ----
    {
        const int h  = tid >> 6;             // 0..7
        const int tq = tid & 63;
        const v2f* pek2 = (const v2f*)(ws + OFF_PEK);   // element (jp*128 + t)
        const v2f* qh0 = (const v2f*)(qs[0] + h * 32);  // 16 j-pairs
        const v2f* qh1 = (const v2f*)(qs[1] + h * 32);
        v2f b00 = {0.f, 0.f}, b01 = {0.f, 0.f}, b10 = {0.f, 0.f}, b11 = {0.f, 0.f};
        #pragma unroll
        for (int jp = 0; jp < 16; ++jp) {
            const v2f q0 = qh0[jp];
            const v2f q1 = qh1[jp];
            const v2f pA = pek2[(h * 16 + jp) * 128 + tq];       // 8B/lane coalesced
            const v2f pB = pek2[(h * 16 + jp) * 128 + tq + 64];
            b00 = pkfma(q0, pA, b00);
            b01 = pkfma(q0, pB, b01);
            b10 = pkfma(q1, pA, b10);
            b11 = pkfma(q1, pB, b11);
        }
        combo[0][2048 + h * NT + tq]      = b00.x + b00.y;
        combo[0][2048 + h * NT + tq + 64] = b01.x + b01.y;
        combo[1][2048 + h * NT + tq]      = b10.x + b10.y;
        combo[1][2048 + h * NT + tq + 64] = b11.x + b11.y;
    }
    __syncthreads();

    // ---- Phase F (per half): softmax over t<Lh with pe corrections ----
    if (Lh > 0) {
        const float* sc   = &combo[half][0];
        const float* mvb  = sc + 1024;
        const float* qkxp = sc + 2048;
        const float* pemv = ws + OFF_PEMV;
        const int wv = lt >> 6, lane = lt & 63;
        float wsum = 0.f;
        for (int hh2 = 0; hh2 < 2; ++hh2) {
            const int h = wv * 2 + hh2;
            float s1 = (lane < Lh) ? sc[h * NT + lane] + qkxp[h * NT + lane] : -3e38f;
            float s2 = (lane + 64 < Lh) ? sc[h * NT + 64 + lane] + qkxp[h * NT + 64 + lane] : -3e38f;
            float mx = fmaxf(s1, s2);
            #pragma unroll
            for (int off = 32; off > 0; off >>= 1)
                mx = fmaxf(mx, __shfl_down(mx, off, 64));
            mx = __shfl(mx, 0, 64);
            const float vbv = ws[OFF_EVA + ah * NH + h];
            float e1 = (lane < Lh) ? __expf(s1 - mx) : 0.f;
            float e2 = (lane + 64 < Lh) ? __expf(s2 - mx) : 0.f;
            float num = e1 * (mvb[h * NT + lane] + pemv[h * NT + lane] + vbv);
            num = fmaf(e2, mvb[h * NT + 64 + lane] + pemv[h * NT + 64 + lane] + vbv, num);
            float den = e1 + e2;
            #pragma unroll
            for (int off = 32; off > 0; off >>= 1) {
                num += __shfl_down(num, off, 64);
                den += __shfl_down(den, off, 64);
            }
            if (lane == 0) wsum += num / den;
        }
        if (lane == 0) red[half][wv] = wsum;
    }
    __syncthreads();
    if (lt == 0 && Lh > 0)
        atomicAdd(ws + OFF_SB + bh,
                  cstp[7] + red[half][0] + red[half][1] + red[half][2] + red[half][3]);
}

__global__ __launch_bounds__(64) void final_kernel(
    const float* __restrict__ statics, const int* __restrict__ lengths,
    const float* __restrict__ ws, float* __restrict__ out)
{
    const int b = threadIdx.x;   // 64 threads, one per batch
    const float* cst = ws + OFF_CST;
    int n = 0;
    for (int a = 0; a < NA; ++a)
        if (lengths[b * NA + a] > 0) ++n;
    float o = ws[OFF_SB + b] / ((float)n + 1e-9f);
    #pragma unroll
    for (int i = 0; i < NS; ++i)
        o = fmaf(statics[b * NS + i], cst[i], o);
    o += cst[6];
    out[b] = o;
}

extern "C" void kernel_launch(void* const* d_in, const int* in_sizes, int n_in,
                              void* d_out, int out_size, void* d_ws, size_t ws_size,
                              hipStream_t stream) {
    const float* data     = (const float*)d_in[0];
    // d_in[1] = time  (implied by mask; unused)
    const int*   mask     = (const int*)d_in[2];
    const float* statics  = (const float*)d_in[3];
    const float* W_embed  = (const float*)d_in[4];
    const float* b_embed  = (const float*)d_in[5];
    const float* E_var    = (const float*)d_in[6];
    const float* W_static = (const float*)d_in[7];
    const float* b_static = (const float*)d_in[8];
    const float* Wq       = (const float*)d_in[9];
    const float* bq       = (const float*)d_in[10];
    const float* Wk       = (const float*)d_in[11];
    // d_in[12] = bk (uniform over t -> cancels in softmax; unused)
    const float* Wv       = (const float*)d_in[13];
    const float* bv       = (const float*)d_in[14];
    const float* Wo       = (const float*)d_in[15];
    const float* bo       = (const float*)d_in[16];
    const float* Wg       = (const float*)d_in[17];
    const float* bg       = (const float*)d_in[18];
    float* out = (float*)d_out;
    float* ws  = (float*)d_ws;

    setup1_kernel<<<dim3(393), dim3(256), 0, stream>>>(Wk, Wv, Wo, Wg, bv, bo,
                                                       W_static, b_static, bg, E_var, ws);
    setup2_kernel<<<dim3(128), dim3(256), 0, stream>>>(Wk, ws);
    main_kernel<<<dim3(NB * NA / 2), dim3(512), 0, stream>>>(data, mask, W_embed, b_embed,
                                                             E_var, Wq, bq, ws);
    final_kernel<<<dim3(1), dim3(64), 0, stream>>>(statics, mask, ws, out);
}